// Round 10
// baseline (965.702 us; speedup 1.0000x reference)
//
#include <hip/hip_runtime.h>
#include <hip/hip_bf16.h>

// Problem constants
constexpr int NB = 4;        // batch
constexpr int CC = 128;      // channels
constexpr int HW = 65536;    // 256*256 pixels per (b, channel) plane
// windows: 32x32 = 1024 per batch, 8x8 = 64 px per window

using bf16x8 = __attribute__((ext_vector_type(8))) short;   // MFMA A/B frag (4 VGPR)
using f32x4  = __attribute__((ext_vector_type(4))) float;   // MFMA C/D frag

__device__ __forceinline__ unsigned short f2bf(float f) {
  unsigned u = __builtin_bit_cast(unsigned, f);
  u += 0x7FFFu + ((u >> 16) & 1u);
  return (unsigned short)(u >> 16);
}
__device__ __forceinline__ float bf2f(unsigned short s) {
  return __builtin_bit_cast(float, (unsigned)s << 16);
}

// Swizzled byte offsets (T2): rows of 128 B (64 bf16) / 256 B (128 bf16).
// XOR of byte bits 4..6 (resp 4..7) with low row bits; involution, 16B-aligned
// accesses stay aligned. Verified <=2-way banks on all read/write patterns.
__device__ __forceinline__ int swz128(int row, int b) { return row * 128 + (b ^ ((row & 7) << 4)); }
__device__ __forceinline__ int swz256(int row, int b) { return row * 256 + (b ^ ((row & 15) << 4)); }

// 64-channel half-halo: halo[ch*168 + r*16 + slot], r=0..9 (image row ih0-1+r)
// slot 0..7 window px, 8 = right halo, 9 = left halo. 21504 B.
__device__ __forceinline__ uint4 hload(const __hip_bfloat16* __restrict__ base,
                                       int ih0, int iw0, int idx) {
  int ch = idx / 30;
  int rem = idx - ch * 30;
  int r = rem / 3, c = rem - r * 3;
  int ii = ih0 - 1 + r, j0 = iw0 - 8 + c * 8;
  uint4 v = {0u, 0u, 0u, 0u};
  if (idx < 1920 && (unsigned)ii < 256u && (unsigned)j0 <= 248u)
    v = *(const uint4*)(base + (((size_t)ch) << 16) + (ii << 8) + j0);
  return v;
}
__device__ __forceinline__ void hstore(unsigned short* __restrict__ halo, int idx, uint4 v) {
  if (idx >= 1920) return;
  int ch = idx / 30;
  int rem = idx - ch * 30;
  int r = rem / 3, c = rem - r * 3;
  unsigned short* hrow = halo + ch * 168 + r * 16;
  if (c == 1) *(uint4*)hrow = v;
  else if (c == 0) hrow[9] = (unsigned short)(v.w >> 16);
  else hrow[8] = (unsigned short)(v.x & 0xFFFFu);
}

// dw 3x3 for one (local ch, pr) output row of 8 px.
__device__ __forceinline__ void dw_row(const unsigned short* __restrict__ halo,
                                       const float* __restrict__ wd,
                                       int chl, int pr, float* __restrict__ outv) {
#pragma unroll
  for (int pc = 0; pc < 8; ++pc) outv[pc] = 0.f;
#pragma unroll
  for (int kr = 0; kr < 3; ++kr) {
    const unsigned short* hrow = halo + chl * 168 + (pr + kr) * 16;
    uint4 rw = *(const uint4*)hrow;
    float rv[10];
    rv[0] = bf2f((unsigned short)(rw.x & 0xFFFFu));
    rv[1] = bf2f((unsigned short)(rw.x >> 16));
    rv[2] = bf2f((unsigned short)(rw.y & 0xFFFFu));
    rv[3] = bf2f((unsigned short)(rw.y >> 16));
    rv[4] = bf2f((unsigned short)(rw.z & 0xFFFFu));
    rv[5] = bf2f((unsigned short)(rw.z >> 16));
    rv[6] = bf2f((unsigned short)(rw.w & 0xFFFFu));
    rv[7] = bf2f((unsigned short)(rw.w >> 16));
    rv[8] = bf2f(hrow[8]);
    rv[9] = bf2f(hrow[9]);
#pragma unroll
    for (int s = 0; s < 3; ++s) {
      float wv = wd[kr * 3 + s];
#pragma unroll
      for (int pc = 0; pc < 8; ++pc) {
        int m = pc + s - 1;
        float xv = (m < 0) ? rv[9] : rv[m];
        outv[pc] = fmaf(wv, xv, outv[pc]);
      }
    }
  }
}

// dw for one half (2 tasks); optionally accumulate sumsq.
template <bool SQ>
__device__ __forceinline__ void dw_half(const unsigned short* __restrict__ halo,
                                        const float* __restrict__ wdw_g,
                                        int g0, int ch_l, int pr, int half,
                                        float (*outv)[8], float* __restrict__ ssq) {
#pragma unroll
  for (int it = 0; it < 2; ++it) {
    int chl = (g0 + 2 * it) * 16 + ch_l;   // local 0..63
    int chf = half * 64 + chl;             // full 0..127
    float wd[9];
#pragma unroll
    for (int kk = 0; kk < 9; ++kk) wd[kk] = wdw_g[chf * 9 + kk];
    dw_row(halo, wd, chl, pr, outv[it]);
    if (SQ) {
#pragma unroll
      for (int pc = 0; pc < 8; ++pc)
        ssq[pc] = fmaf(outv[it][pc], outv[it][pc], ssq[pc]);
    }
  }
}

// =======================================================================
// Kernel 1: rolled 1x1 conv as bf16 MFMA GEMM (math unchanged; VGPR capped
// to 168 via launch_bounds(256,3): was 256 -> only 2 waves/SIMD).
// =======================================================================
__global__ __launch_bounds__(256, 3) void k_qkv_mfma(const float* __restrict__ x,
                                                     const float* __restrict__ wq,
                                                     __hip_bfloat16* __restrict__ qkv) {
  __shared__ unsigned short x_s[128 * 136];   // [px][c]

  int blk = blockIdx.x;                 // 4 b x 256 i x 2 j-half
  int b = blk >> 9, i = (blk >> 1) & 255, jh = blk & 1;
  int j0 = jh << 7;
  int si = (i + 4) & 255;               // roll(-4): source row
  int t = threadIdx.x;

  {
    int c0 = (t & 63) << 1;
    int jb = (t >> 6) << 5;
    const float* xr0 = x + (((size_t)(b * CC + c0)) << 16) + (si << 8);
    const float* xr1 = xr0 + HW;
#pragma unroll
    for (int u = 0; u < 8; ++u) {
      int jj = jb + (u << 2);
      int sj = j0 + jj + 4;
      float v0[4], v1[4];
      if (sj + 3 <= 255) {
        *(float4*)v0 = *(const float4*)(xr0 + sj);
        *(float4*)v1 = *(const float4*)(xr1 + sj);
      } else {
#pragma unroll
        for (int e = 0; e < 4; ++e) {
          int s = (sj + e) & 255;
          v0[e] = xr0[s];
          v1[e] = xr1[s];
        }
      }
#pragma unroll
      for (int e = 0; e < 4; ++e) {
        unsigned pk = (unsigned)f2bf(v0[e]) | ((unsigned)f2bf(v1[e]) << 16);
        *(unsigned*)&x_s[(jj + e) * 136 + c0] = pk;
      }
    }
  }
  __syncthreads();

  int w = t >> 6;
  int lane = t & 63;
  int col = lane & 15;
  int kg = lane >> 4;

#pragma unroll 1
  for (int oi = 0; oi < 3; ++oi) {
    int m0 = oi * 128 + w * 32;
    bf16x8 afr[2][4];
#pragma unroll
    for (int mt = 0; mt < 2; ++mt) {
      const float* wr = wq + (m0 + mt * 16 + col) * CC + kg * 8;
#pragma unroll
      for (int ks = 0; ks < 4; ++ks) {
        float wa[4], wb[4];
        *(float4*)wa = *(const float4*)(wr + ks * 32);
        *(float4*)wb = *(const float4*)(wr + ks * 32 + 4);
        bf16x8 f;
#pragma unroll
        for (int e = 0; e < 4; ++e) {
          f[e] = (short)f2bf(wa[e]);
          f[e + 4] = (short)f2bf(wb[e]);
        }
        afr[mt][ks] = f;
      }
    }
#pragma unroll 1
    for (int n = 0; n < 8; ++n) {
      int px = n * 16 + col;
      f32x4 acc0 = {0.f, 0.f, 0.f, 0.f};
      f32x4 acc1 = {0.f, 0.f, 0.f, 0.f};
#pragma unroll
      for (int ks = 0; ks < 4; ++ks) {
        bf16x8 bfr = *(const bf16x8*)&x_s[px * 136 + ks * 32 + kg * 8];
        acc0 = __builtin_amdgcn_mfma_f32_16x16x32_bf16(afr[0][ks], bfr, acc0, 0, 0, 0);
        acc1 = __builtin_amdgcn_mfma_f32_16x16x32_bf16(afr[1][ks], bfr, acc1, 0, 0, 0);
      }
      int j = j0 + n * 16 + col;
#pragma unroll
      for (int r = 0; r < 4; ++r) {
        int och0 = m0 + kg * 4 + r;
        int och1 = m0 + 16 + kg * 4 + r;
        int g0 = och0 >> 7, c0 = och0 & 127;
        int g1 = och1 >> 7, c1 = och1 & 127;
        qkv[(((size_t)((g0 * NB + b) * CC + c0)) << 16) + (i << 8) + j] =
            __float2bfloat16(acc0[r]);
        qkv[(((size_t)((g1 * NB + b) * CC + c1)) << 16) + (i << 8) + j] =
            __float2bfloat16(acc1[r]);
      }
    }
  }
}

// =======================================================================
// Kernel 2 (FUSED, 3 blocks/CU): manual LDS layout, 54272 B total:
//   halo (21504) : q0|q1|k0|k1|v0|v1 half-halos, ping-ponged
//   RB   (16384) : q_t[128r x 128B, swz128] -> v_t[64r x 256B, swz256] -> po_t
//   RC   (16384) : k_t[swz128] -> a_t half [128d x 64c, swz128], 2 passes
// Sumsq entirely in registers (wave-aligned pr mapping + shfl_xor(32)).
// =======================================================================
__global__ __launch_bounds__(256, 3) void k_fused(const __hip_bfloat16* __restrict__ qkv,
                                                  const float* __restrict__ wdw,
                                                  const float* __restrict__ temp_p,
                                                  const float* __restrict__ wp,
                                                  float* __restrict__ attn_out,
                                                  float* __restrict__ y) {
  __shared__ __align__(16) char smem[54272];
  unsigned short* halo = (unsigned short*)smem;
  char* RB = smem + 21504;
  char* RC = smem + 21504 + 16384;

  int bid = blockIdx.x;
  int blk = ((bid & 7) << 9) + (bid >> 3);   // XCD swizzle (4096 % 8 == 0)
  int b = blk >> 10, n = blk & 1023;
  int ih0 = (n >> 5) << 3, iw0 = (n & 31) << 3;
  int t = threadIdx.x;
  int ch_l = t & 15;
  int wv = t >> 6, lane = t & 63;
  int col = lane & 15, kg = lane >> 4;
  int giw = (t >> 4) & 3;
  int pr = 2 * wv + (giw & 1);    // this thread's pixel row (all its dw tasks)
  int g0 = giw >> 1;              // chgrp base {0,1}; tasks cover {g0, g0+2}
  float tau = temp_p[0];
  const __hip_bfloat16* qb = qkv + (((size_t)(b * CC)) << 16);
  const __hip_bfloat16* kb = qb + (((size_t)(NB * CC)) << 16);
  const __hip_bfloat16* vb = qb + (((size_t)(2 * NB * CC)) << 16);
  const size_t HALF = ((size_t)64) << 16;

  uint4 pre[8];
  float outv[4][8];     // q/k: 2 halves x 2 tasks persist for scale
  float ssq[8];

  // ---- P0: stage q-h0 directly
#pragma unroll
  for (int it = 0; it < 8; ++it) {
    int idx = it * 256 + t;
    hstore(halo, idx, hload(qb, ih0, iw0, idx));
  }
  __syncthreads();                                           // B1
  // ---- P1: prefetch q-h1; dw q-h0
#pragma unroll
  for (int it = 0; it < 8; ++it) pre[it] = hload(qb + HALF, ih0, iw0, it * 256 + t);
#pragma unroll
  for (int pc = 0; pc < 8; ++pc) ssq[pc] = 0.f;
  dw_half<true>(halo, wdw, g0, ch_l, pr, 0, &outv[0], ssq);
  __syncthreads();                                           // B2
  // ---- P2: store q-h1
#pragma unroll
  for (int it = 0; it < 8; ++it) hstore(halo, it * 256 + t, pre[it]);
  __syncthreads();                                           // B3
  // ---- P3: prefetch k-h0; dw q-h1; reduce; write q_t
#pragma unroll
  for (int it = 0; it < 8; ++it) pre[it] = hload(kb, ih0, iw0, it * 256 + t);
  dw_half<true>(halo, wdw, g0, ch_l, pr, 1, &outv[2], ssq);
  {
    float psv[8];
#pragma unroll
    for (int pc = 0; pc < 8; ++pc) {
      float s = ssq[pc];
      s += __shfl_xor(s, 1); s += __shfl_xor(s, 2);
      s += __shfl_xor(s, 4); s += __shfl_xor(s, 8);
      s += __shfl_xor(s, 32);            // partner grp (g0^1) -> full 128 ch
      psv[pc] = 1.f / fmaxf(sqrtf(s), 1e-12f);
    }
#pragma unroll
    for (int tk = 0; tk < 4; ++tk) {
      int chf = (tk >> 1) * 64 + (g0 + 2 * (tk & 1)) * 16 + ch_l;
      unsigned short o8[8];
#pragma unroll
      for (int pc = 0; pc < 8; ++pc) o8[pc] = f2bf(outv[tk][pc] * psv[pc]);
      *(uint4*)(RB + swz128(chf, pr * 16)) = *(const uint4*)o8;
    }
  }
  __syncthreads();                                           // B4
  // ---- P4: store k-h0
#pragma unroll
  for (int it = 0; it < 8; ++it) hstore(halo, it * 256 + t, pre[it]);
  __syncthreads();                                           // B5
  // ---- P5: prefetch k-h1; dw k-h0
#pragma unroll
  for (int it = 0; it < 8; ++it) pre[it] = hload(kb + HALF, ih0, iw0, it * 256 + t);
#pragma unroll
  for (int pc = 0; pc < 8; ++pc) ssq[pc] = 0.f;
  dw_half<true>(halo, wdw + CC * 9, g0, ch_l, pr, 0, &outv[0], ssq);
  __syncthreads();                                           // B6
  // ---- P6: store k-h1
#pragma unroll
  for (int it = 0; it < 8; ++it) hstore(halo, it * 256 + t, pre[it]);
  __syncthreads();                                           // B7
  // ---- P7: prefetch v-h0; dw k-h1; reduce; write k_t (tau folded)
#pragma unroll
  for (int it = 0; it < 8; ++it) pre[it] = hload(vb, ih0, iw0, it * 256 + t);
  dw_half<true>(halo, wdw + CC * 9, g0, ch_l, pr, 1, &outv[2], ssq);
  {
    float psv[8];
#pragma unroll
    for (int pc = 0; pc < 8; ++pc) {
      float s = ssq[pc];
      s += __shfl_xor(s, 1); s += __shfl_xor(s, 2);
      s += __shfl_xor(s, 4); s += __shfl_xor(s, 8);
      s += __shfl_xor(s, 32);
      psv[pc] = tau / fmaxf(sqrtf(s), 1e-12f);
    }
#pragma unroll
    for (int tk = 0; tk < 4; ++tk) {
      int chf = (tk >> 1) * 64 + (g0 + 2 * (tk & 1)) * 16 + ch_l;
      unsigned short o8[8];
#pragma unroll
      for (int pc = 0; pc < 8; ++pc) o8[pc] = f2bf(outv[tk][pc] * psv[pc]);
      *(uint4*)(RC + swz128(chf, pr * 16)) = *(const uint4*)o8;
    }
  }
  __syncthreads();                                           // B8
  // ---- P8: store v-h0
#pragma unroll
  for (int it = 0; it < 8; ++it) hstore(halo, it * 256 + t, pre[it]);
  __syncthreads();                                           // B9
  // ---- P9: prefetch v-h1; QK^T (q_t=RB, k_t=RC); relu; attn write; keep regs
#pragma unroll
  for (int it = 0; it < 8; ++it) pre[it] = hload(vb + HALF, ih0, iw0, it * 256 + t);
  int c0 = wv * 32;
  f32x4 pa0[8], pa1[8];
  {
    bf16x8 afr[2][2];
#pragma unroll
    for (int mt = 0; mt < 2; ++mt)
#pragma unroll
      for (int ks = 0; ks < 2; ++ks)
        afr[mt][ks] = *(const bf16x8*)(RB + swz128(c0 + mt * 16 + col, ks * 64 + kg * 16));
    float* ao = attn_out + ((size_t)blk << 14);   // 128*128 per window
#pragma unroll
    for (int dt = 0; dt < 8; ++dt) {
      bf16x8 b0 = *(const bf16x8*)(RC + swz128(dt * 16 + col, kg * 16));
      bf16x8 b1 = *(const bf16x8*)(RC + swz128(dt * 16 + col, 64 + kg * 16));
      f32x4 a0 = {0.f, 0.f, 0.f, 0.f};
      f32x4 a1 = {0.f, 0.f, 0.f, 0.f};
      a0 = __builtin_amdgcn_mfma_f32_16x16x32_bf16(afr[0][0], b0, a0, 0, 0, 0);
      a0 = __builtin_amdgcn_mfma_f32_16x16x32_bf16(afr[0][1], b1, a0, 0, 0, 0);
      a1 = __builtin_amdgcn_mfma_f32_16x16x32_bf16(afr[1][0], b0, a1, 0, 0, 0);
      a1 = __builtin_amdgcn_mfma_f32_16x16x32_bf16(afr[1][1], b1, a1, 0, 0, 0);
#pragma unroll
      for (int r = 0; r < 4; ++r) {
        a0[r] = fmaxf(a0[r], 0.f);
        a1[r] = fmaxf(a1[r], 0.f);
        ao[((c0 + kg * 4 + r) << 7) + dt * 16 + col] = a0[r];
        ao[((c0 + 16 + kg * 4 + r) << 7) + dt * 16 + col] = a1[r];
      }
      pa0[dt] = a0;
      pa1[dt] = a1;
    }
  }
  __syncthreads();                                           // B10 (q_t/k_t dead)
  // ---- P10: dw v-h0 -> v_t cols 0..63 (RB); waves 0,1 write a_t half0 (RC)
  {
    float vo[2][8];
    dw_half<false>(halo, wdw + 2 * CC * 9, g0, ch_l, pr, 0, vo, nullptr);
#pragma unroll
    for (int it = 0; it < 2; ++it) {
      int chf = (g0 + 2 * it) * 16 + ch_l;   // 0..63
#pragma unroll
      for (int pc = 0; pc < 8; ++pc)
        *(unsigned short*)(RB + swz256(pr * 8 + pc, chf * 2)) = f2bf(vo[it][pc]);
    }
  }
  if (wv < 2) {
#pragma unroll
    for (int dt = 0; dt < 8; ++dt)
#pragma unroll
      for (int r = 0; r < 4; ++r) {
        int d = dt * 16 + col;
        *(unsigned short*)(RC + swz128(d, (c0 + kg * 4 + r) * 2)) = f2bf(pa0[dt][r]);
        *(unsigned short*)(RC + swz128(d, (c0 + 16 + kg * 4 + r) * 2)) = f2bf(pa1[dt][r]);
      }
  }
  __syncthreads();                                           // B11
  // ---- P11: store v-h1; PV part1 (ks 0,1)
#pragma unroll
  for (int it = 0; it < 8; ++it) hstore(halo, it * 256 + t, pre[it]);
  f32x4 pacc[8];
#pragma unroll
  for (int dt = 0; dt < 8; ++dt) pacc[dt] = {0.f, 0.f, 0.f, 0.f};
#pragma unroll
  for (int ks = 0; ks < 2; ++ks) {
    bf16x8 va = *(const bf16x8*)(RB + swz256(wv * 16 + col, ks * 64 + kg * 16));
#pragma unroll
    for (int dt = 0; dt < 8; ++dt) {
      bf16x8 bf = *(const bf16x8*)(RC + swz128(dt * 16 + col, (ks & 1) * 64 + kg * 16));
      pacc[dt] = __builtin_amdgcn_mfma_f32_16x16x32_bf16(va, bf, pacc[dt], 0, 0, 0);
    }
  }
  __syncthreads();                                           // B12
  // ---- P12: dw v-h1 -> v_t cols 64..127; waves 2,3 write a_t half1
  {
    float vo[2][8];
    dw_half<false>(halo, wdw + 2 * CC * 9, g0, ch_l, pr, 1, vo, nullptr);
#pragma unroll
    for (int it = 0; it < 2; ++it) {
      int chf = 64 + (g0 + 2 * it) * 16 + ch_l;   // 64..127
#pragma unroll
      for (int pc = 0; pc < 8; ++pc)
        *(unsigned short*)(RB + swz256(pr * 8 + pc, chf * 2)) = f2bf(vo[it][pc]);
    }
  }
  if (wv >= 2) {
    int cl0 = c0 - 64;   // 0 or 32
#pragma unroll
    for (int dt = 0; dt < 8; ++dt)
#pragma unroll
      for (int r = 0; r < 4; ++r) {
        int d = dt * 16 + col;
        *(unsigned short*)(RC + swz128(d, (cl0 + kg * 4 + r) * 2)) = f2bf(pa0[dt][r]);
        *(unsigned short*)(RC + swz128(d, (cl0 + 16 + kg * 4 + r) * 2)) = f2bf(pa1[dt][r]);
      }
  }
  __syncthreads();                                           // B13
  // ---- P13: PV part2 (ks 2,3)
#pragma unroll
  for (int ks = 2; ks < 4; ++ks) {
    bf16x8 va = *(const bf16x8*)(RB + swz256(wv * 16 + col, ks * 64 + kg * 16));
#pragma unroll
    for (int dt = 0; dt < 8; ++dt) {
      bf16x8 bf = *(const bf16x8*)(RC + swz128(dt * 16 + col, (ks & 1) * 64 + kg * 16));
      pacc[dt] = __builtin_amdgcn_mfma_f32_16x16x32_bf16(va, bf, pacc[dt], 0, 0, 0);
    }
  }
  __syncthreads();                                           // B14 (v_t dead)
  // ---- P14: po_t[p][d] bf16 (RB, swz256)
#pragma unroll
  for (int dt = 0; dt < 8; ++dt)
#pragma unroll
    for (int r = 0; r < 4; ++r)
      *(unsigned short*)(RB + swz256(wv * 16 + kg * 4 + r, (dt * 16 + col) * 2)) =
          f2bf(pacc[dt][r]);
  __syncthreads();                                           // B15
  // ---- P15: proj (Wp A-frags from global) + fused unwindow/roll y store
  {
    int p = wv * 16 + col;
    bf16x8 bfr[4];
#pragma unroll
    for (int ks = 0; ks < 4; ++ks)
      bfr[ks] = *(const bf16x8*)(RB + swz256(p, ks * 64 + kg * 16));
    int i_f = (((n >> 5) << 3) + (p >> 3) + 4) & 255;
    int j_f = (((n & 31) << 3) + (p & 7) + 4) & 255;
    float* yp = y + (((size_t)b * CC) << 16) + (i_f << 8) + j_f;
#pragma unroll
    for (int mt = 0; mt < 8; ++mt) {
      bf16x8 afr[4];
      const float* wr = wp + (mt * 16 + col) * CC + kg * 8;
#pragma unroll
      for (int ks = 0; ks < 4; ++ks) {
        float wa[4], wb[4];
        *(float4*)wa = *(const float4*)(wr + ks * 32);
        *(float4*)wb = *(const float4*)(wr + ks * 32 + 4);
        bf16x8 f;
#pragma unroll
        for (int e = 0; e < 4; ++e) {
          f[e] = (short)f2bf(wa[e]);
          f[e + 4] = (short)f2bf(wb[e]);
        }
        afr[ks] = f;
      }
      f32x4 acc = {0.f, 0.f, 0.f, 0.f};
#pragma unroll
      for (int ks = 0; ks < 4; ++ks)
        acc = __builtin_amdgcn_mfma_f32_16x16x32_bf16(afr[ks], bfr[ks], acc, 0, 0, 0);
#pragma unroll
      for (int r = 0; r < 4; ++r) {
        int och = mt * 16 + kg * 4 + r;
        yp[(size_t)och << 16] = acc[r];
      }
    }
  }
}

extern "C" void kernel_launch(void* const* d_in, const int* in_sizes, int n_in,
                              void* d_out, int out_size, void* d_ws, size_t ws_size,
                              hipStream_t stream) {
  const float* x = (const float*)d_in[0];
  const float* w_qkv = (const float*)d_in[1];
  const float* w_dw = (const float*)d_in[2];
  const float* w_proj = (const float*)d_in[3];
  const float* temp = (const float*)d_in[4];
  float* y = (float*)d_out;
  float* attn = (float*)d_out + (size_t)NB * CC * HW;   // y first, then attn

  // d_ws (bf16): qkv [3][b][c][hw] = 201 MB.
  __hip_bfloat16* qkv = (__hip_bfloat16*)d_ws;

  k_qkv_mfma<<<2048, 256, 0, stream>>>(x, w_qkv, qkv);
  k_fused<<<4096, 256, 0, stream>>>(qkv, w_dw, temp, w_proj, attn, y);
}

// Round 11
// 795.947 us; speedup vs baseline: 1.2133x; 1.2133x over previous
//
#include <hip/hip_runtime.h>
#include <hip/hip_bf16.h>

// Problem constants
constexpr int NB = 4;        // batch
constexpr int CC = 128;      // channels
constexpr int HW = 65536;    // 256*256 pixels per (b, channel) plane
// windows: 32x32 = 1024 per batch, 8x8 = 64 px per window

using bf16x8 = __attribute__((ext_vector_type(8))) short;   // MFMA A/B frag (4 VGPR)
using f32x4  = __attribute__((ext_vector_type(4))) float;   // MFMA C/D frag

__device__ __forceinline__ unsigned short f2bf(float f) {
  unsigned u = __builtin_bit_cast(unsigned, f);
  u += 0x7FFFu + ((u >> 16) & 1u);
  return (unsigned short)(u >> 16);
}
__device__ __forceinline__ float bf2f(unsigned short s) {
  return __builtin_bit_cast(float, (unsigned)s << 16);
}

// Swizzled byte offsets (T2): rows of 128 B (64 bf16) / 256 B (128 bf16).
__device__ __forceinline__ int swz128(int row, int b) { return row * 128 + (b ^ ((row & 7) << 4)); }
__device__ __forceinline__ int swz256(int row, int b) { return row * 256 + (b ^ ((row & 15) << 4)); }

// 64-channel half-halo: halo[ch*168 + r*16 + slot], r=0..9 (image row ih0-1+r)
// slot 0..7 window px, 8 = right halo, 9 = left halo. 21504 B.
__device__ __forceinline__ uint4 hload(const __hip_bfloat16* __restrict__ base,
                                       int ih0, int iw0, int idx) {
  int ch = idx / 30;
  int rem = idx - ch * 30;
  int r = rem / 3, c = rem - r * 3;
  int ii = ih0 - 1 + r, j0 = iw0 - 8 + c * 8;
  uint4 v = {0u, 0u, 0u, 0u};
  if (idx < 1920 && (unsigned)ii < 256u && (unsigned)j0 <= 248u)
    v = *(const uint4*)(base + (((size_t)ch) << 16) + (ii << 8) + j0);
  return v;
}
__device__ __forceinline__ void hstore(unsigned short* __restrict__ halo, int idx, uint4 v) {
  if (idx >= 1920) return;
  int ch = idx / 30;
  int rem = idx - ch * 30;
  int r = rem / 3, c = rem - r * 3;
  unsigned short* hrow = halo + ch * 168 + r * 16;
  if (c == 1) *(uint4*)hrow = v;
  else if (c == 0) hrow[9] = (unsigned short)(v.w >> 16);
  else hrow[8] = (unsigned short)(v.x & 0xFFFFu);
}

// dw 3x3 for one (local ch, pr) output row of 8 px.
__device__ __forceinline__ void dw_row(const unsigned short* __restrict__ halo,
                                       const float* __restrict__ wd,
                                       int chl, int pr, float* __restrict__ outv) {
#pragma unroll
  for (int pc = 0; pc < 8; ++pc) outv[pc] = 0.f;
#pragma unroll
  for (int kr = 0; kr < 3; ++kr) {
    const unsigned short* hrow = halo + chl * 168 + (pr + kr) * 16;
    uint4 rw = *(const uint4*)hrow;
    float rv[10];
    rv[0] = bf2f((unsigned short)(rw.x & 0xFFFFu));
    rv[1] = bf2f((unsigned short)(rw.x >> 16));
    rv[2] = bf2f((unsigned short)(rw.y & 0xFFFFu));
    rv[3] = bf2f((unsigned short)(rw.y >> 16));
    rv[4] = bf2f((unsigned short)(rw.z & 0xFFFFu));
    rv[5] = bf2f((unsigned short)(rw.z >> 16));
    rv[6] = bf2f((unsigned short)(rw.w & 0xFFFFu));
    rv[7] = bf2f((unsigned short)(rw.w >> 16));
    rv[8] = bf2f(hrow[8]);
    rv[9] = bf2f(hrow[9]);
#pragma unroll
    for (int s = 0; s < 3; ++s) {
      float wv = wd[kr * 3 + s];
#pragma unroll
      for (int pc = 0; pc < 8; ++pc) {
        int m = pc + s - 1;
        float xv = (m < 0) ? rv[9] : rv[m];
        outv[pc] = fmaf(wv, xv, outv[pc]);
      }
    }
  }
}

// dw for one half (2 tasks); optionally accumulate sumsq.
template <bool SQ>
__device__ __forceinline__ void dw_half(const unsigned short* __restrict__ halo,
                                        const float* __restrict__ wdw_g,
                                        int g0, int ch_l, int pr, int half,
                                        float (*outv)[8], float* __restrict__ ssq) {
#pragma unroll
  for (int it = 0; it < 2; ++it) {
    int chl = (g0 + 2 * it) * 16 + ch_l;   // local 0..63
    int chf = half * 64 + chl;             // full 0..127
    float wd[9];
#pragma unroll
    for (int kk = 0; kk < 9; ++kk) wd[kk] = wdw_g[chf * 9 + kk];
    dw_row(halo, wd, chl, pr, outv[it]);
    if (SQ) {
#pragma unroll
      for (int pc = 0; pc < 8; ++pc)
        ssq[pc] = fmaf(outv[it][pc], outv[it][pc], ssq[pc]);
    }
  }
}

// =======================================================================
// Kernel 1: rolled 1x1 conv as bf16 MFMA GEMM.
// ROUND-11: plain launch_bounds(256) — the (256,3) hint in round 10 capped
// VGPR at 84 (<< live set) and caused massive scratch spills (+368 MB writes).
// =======================================================================
__global__ __launch_bounds__(256) void k_qkv_mfma(const float* __restrict__ x,
                                                  const float* __restrict__ wq,
                                                  __hip_bfloat16* __restrict__ qkv) {
  __shared__ unsigned short x_s[128 * 136];   // [px][c]

  int blk = blockIdx.x;                 // 4 b x 256 i x 2 j-half
  int b = blk >> 9, i = (blk >> 1) & 255, jh = blk & 1;
  int j0 = jh << 7;
  int si = (i + 4) & 255;               // roll(-4): source row
  int t = threadIdx.x;

  {
    int c0 = (t & 63) << 1;
    int jb = (t >> 6) << 5;
    const float* xr0 = x + (((size_t)(b * CC + c0)) << 16) + (si << 8);
    const float* xr1 = xr0 + HW;
#pragma unroll
    for (int u = 0; u < 8; ++u) {
      int jj = jb + (u << 2);
      int sj = j0 + jj + 4;
      float v0[4], v1[4];
      if (sj + 3 <= 255) {
        *(float4*)v0 = *(const float4*)(xr0 + sj);
        *(float4*)v1 = *(const float4*)(xr1 + sj);
      } else {
#pragma unroll
        for (int e = 0; e < 4; ++e) {
          int s = (sj + e) & 255;
          v0[e] = xr0[s];
          v1[e] = xr1[s];
        }
      }
#pragma unroll
      for (int e = 0; e < 4; ++e) {
        unsigned pk = (unsigned)f2bf(v0[e]) | ((unsigned)f2bf(v1[e]) << 16);
        *(unsigned*)&x_s[(jj + e) * 136 + c0] = pk;
      }
    }
  }
  __syncthreads();

  int w = t >> 6;
  int lane = t & 63;
  int col = lane & 15;
  int kg = lane >> 4;

#pragma unroll 1
  for (int oi = 0; oi < 3; ++oi) {
    int m0 = oi * 128 + w * 32;
    bf16x8 afr[2][4];
#pragma unroll
    for (int mt = 0; mt < 2; ++mt) {
      const float* wr = wq + (m0 + mt * 16 + col) * CC + kg * 8;
#pragma unroll
      for (int ks = 0; ks < 4; ++ks) {
        float wa[4], wb[4];
        *(float4*)wa = *(const float4*)(wr + ks * 32);
        *(float4*)wb = *(const float4*)(wr + ks * 32 + 4);
        bf16x8 f;
#pragma unroll
        for (int e = 0; e < 4; ++e) {
          f[e] = (short)f2bf(wa[e]);
          f[e + 4] = (short)f2bf(wb[e]);
        }
        afr[mt][ks] = f;
      }
    }
#pragma unroll 1
    for (int n = 0; n < 8; ++n) {
      int px = n * 16 + col;
      f32x4 acc0 = {0.f, 0.f, 0.f, 0.f};
      f32x4 acc1 = {0.f, 0.f, 0.f, 0.f};
#pragma unroll
      for (int ks = 0; ks < 4; ++ks) {
        bf16x8 bfr = *(const bf16x8*)&x_s[px * 136 + ks * 32 + kg * 8];
        acc0 = __builtin_amdgcn_mfma_f32_16x16x32_bf16(afr[0][ks], bfr, acc0, 0, 0, 0);
        acc1 = __builtin_amdgcn_mfma_f32_16x16x32_bf16(afr[1][ks], bfr, acc1, 0, 0, 0);
      }
      int j = j0 + n * 16 + col;
#pragma unroll
      for (int r = 0; r < 4; ++r) {
        int och0 = m0 + kg * 4 + r;
        int och1 = m0 + 16 + kg * 4 + r;
        int g0 = och0 >> 7, c0 = och0 & 127;
        int g1 = och1 >> 7, c1 = och1 & 127;
        qkv[(((size_t)((g0 * NB + b) * CC + c0)) << 16) + (i << 8) + j] =
            __float2bfloat16(acc0[r]);
        qkv[(((size_t)((g1 * NB + b) * CC + c1)) << 16) + (i << 8) + j] =
            __float2bfloat16(acc1[r]);
      }
    }
  }
}

// =======================================================================
// Kernel 2 (FUSED): 54272 B LDS (3 blocks/CU if natural VGPR <= 170):
//   halo (21504) : q0|q1|k0|k1|v0|v1 half-halos, ping-ponged
//   RB   (16384) : q_t[swz128] -> v_t[swz256] -> po_t
//   RC   (16384) : k_t[swz128] -> a_t half [128d x 64c, swz128], 2 passes
// Plain launch_bounds(256): natural VGPR allocation (round-10 cap spilled).
// =======================================================================
__global__ __launch_bounds__(256) void k_fused(const __hip_bfloat16* __restrict__ qkv,
                                               const float* __restrict__ wdw,
                                               const float* __restrict__ temp_p,
                                               const float* __restrict__ wp,
                                               float* __restrict__ attn_out,
                                               float* __restrict__ y) {
  __shared__ __align__(16) char smem[54272];
  unsigned short* halo = (unsigned short*)smem;
  char* RB = smem + 21504;
  char* RC = smem + 21504 + 16384;

  int bid = blockIdx.x;
  int blk = ((bid & 7) << 9) + (bid >> 3);   // XCD swizzle (4096 % 8 == 0)
  int b = blk >> 10, n = blk & 1023;
  int ih0 = (n >> 5) << 3, iw0 = (n & 31) << 3;
  int t = threadIdx.x;
  int ch_l = t & 15;
  int wv = t >> 6, lane = t & 63;
  int col = lane & 15, kg = lane >> 4;
  int giw = (t >> 4) & 3;
  int pr = 2 * wv + (giw & 1);    // this thread's pixel row (all its dw tasks)
  int g0 = giw >> 1;              // chgrp base {0,1}; tasks cover {g0, g0+2}
  float tau = temp_p[0];
  const __hip_bfloat16* qb = qkv + (((size_t)(b * CC)) << 16);
  const __hip_bfloat16* kb = qb + (((size_t)(NB * CC)) << 16);
  const __hip_bfloat16* vb = qb + (((size_t)(2 * NB * CC)) << 16);
  const size_t HALF = ((size_t)64) << 16;

  uint4 pre[8];
  float outv[4][8];     // q/k: 2 halves x 2 tasks persist for scale
  float ssq[8];

  // ---- P0: stage q-h0 directly
#pragma unroll
  for (int it = 0; it < 8; ++it) {
    int idx = it * 256 + t;
    hstore(halo, idx, hload(qb, ih0, iw0, idx));
  }
  __syncthreads();                                           // B1
  // ---- P1: prefetch q-h1; dw q-h0
#pragma unroll
  for (int it = 0; it < 8; ++it) pre[it] = hload(qb + HALF, ih0, iw0, it * 256 + t);
#pragma unroll
  for (int pc = 0; pc < 8; ++pc) ssq[pc] = 0.f;
  dw_half<true>(halo, wdw, g0, ch_l, pr, 0, &outv[0], ssq);
  __syncthreads();                                           // B2
  // ---- P2: store q-h1
#pragma unroll
  for (int it = 0; it < 8; ++it) hstore(halo, it * 256 + t, pre[it]);
  __syncthreads();                                           // B3
  // ---- P3: prefetch k-h0; dw q-h1; reduce; write q_t
#pragma unroll
  for (int it = 0; it < 8; ++it) pre[it] = hload(kb, ih0, iw0, it * 256 + t);
  dw_half<true>(halo, wdw, g0, ch_l, pr, 1, &outv[2], ssq);
  {
    float psv[8];
#pragma unroll
    for (int pc = 0; pc < 8; ++pc) {
      float s = ssq[pc];
      s += __shfl_xor(s, 1); s += __shfl_xor(s, 2);
      s += __shfl_xor(s, 4); s += __shfl_xor(s, 8);
      s += __shfl_xor(s, 32);            // partner grp (g0^1) -> full 128 ch
      psv[pc] = 1.f / fmaxf(sqrtf(s), 1e-12f);
    }
#pragma unroll
    for (int tk = 0; tk < 4; ++tk) {
      int chf = (tk >> 1) * 64 + (g0 + 2 * (tk & 1)) * 16 + ch_l;
      unsigned short o8[8];
#pragma unroll
      for (int pc = 0; pc < 8; ++pc) o8[pc] = f2bf(outv[tk][pc] * psv[pc]);
      *(uint4*)(RB + swz128(chf, pr * 16)) = *(const uint4*)o8;
    }
  }
  __syncthreads();                                           // B4
  // ---- P4: store k-h0
#pragma unroll
  for (int it = 0; it < 8; ++it) hstore(halo, it * 256 + t, pre[it]);
  __syncthreads();                                           // B5
  // ---- P5: prefetch k-h1; dw k-h0
#pragma unroll
  for (int it = 0; it < 8; ++it) pre[it] = hload(kb + HALF, ih0, iw0, it * 256 + t);
#pragma unroll
  for (int pc = 0; pc < 8; ++pc) ssq[pc] = 0.f;
  dw_half<true>(halo, wdw + CC * 9, g0, ch_l, pr, 0, &outv[0], ssq);
  __syncthreads();                                           // B6
  // ---- P6: store k-h1
#pragma unroll
  for (int it = 0; it < 8; ++it) hstore(halo, it * 256 + t, pre[it]);
  __syncthreads();                                           // B7
  // ---- P7: prefetch v-h0; dw k-h1; reduce; write k_t (tau folded)
#pragma unroll
  for (int it = 0; it < 8; ++it) pre[it] = hload(vb, ih0, iw0, it * 256 + t);
  dw_half<true>(halo, wdw + CC * 9, g0, ch_l, pr, 1, &outv[2], ssq);
  {
    float psv[8];
#pragma unroll
    for (int pc = 0; pc < 8; ++pc) {
      float s = ssq[pc];
      s += __shfl_xor(s, 1); s += __shfl_xor(s, 2);
      s += __shfl_xor(s, 4); s += __shfl_xor(s, 8);
      s += __shfl_xor(s, 32);
      psv[pc] = tau / fmaxf(sqrtf(s), 1e-12f);
    }
#pragma unroll
    for (int tk = 0; tk < 4; ++tk) {
      int chf = (tk >> 1) * 64 + (g0 + 2 * (tk & 1)) * 16 + ch_l;
      unsigned short o8[8];
#pragma unroll
      for (int pc = 0; pc < 8; ++pc) o8[pc] = f2bf(outv[tk][pc] * psv[pc]);
      *(uint4*)(RC + swz128(chf, pr * 16)) = *(const uint4*)o8;
    }
  }
  __syncthreads();                                           // B8
  // ---- P8: store v-h0
#pragma unroll
  for (int it = 0; it < 8; ++it) hstore(halo, it * 256 + t, pre[it]);
  __syncthreads();                                           // B9
  // ---- P9: prefetch v-h1; QK^T (q_t=RB, k_t=RC); relu; attn write; keep regs
#pragma unroll
  for (int it = 0; it < 8; ++it) pre[it] = hload(vb + HALF, ih0, iw0, it * 256 + t);
  int c0 = wv * 32;
  f32x4 pa0[8], pa1[8];
  {
    bf16x8 afr[2][2];
#pragma unroll
    for (int mt = 0; mt < 2; ++mt)
#pragma unroll
      for (int ks = 0; ks < 2; ++ks)
        afr[mt][ks] = *(const bf16x8*)(RB + swz128(c0 + mt * 16 + col, ks * 64 + kg * 16));
    float* ao = attn_out + ((size_t)blk << 14);   // 128*128 per window
#pragma unroll
    for (int dt = 0; dt < 8; ++dt) {
      bf16x8 b0 = *(const bf16x8*)(RC + swz128(dt * 16 + col, kg * 16));
      bf16x8 b1 = *(const bf16x8*)(RC + swz128(dt * 16 + col, 64 + kg * 16));
      f32x4 a0 = {0.f, 0.f, 0.f, 0.f};
      f32x4 a1 = {0.f, 0.f, 0.f, 0.f};
      a0 = __builtin_amdgcn_mfma_f32_16x16x32_bf16(afr[0][0], b0, a0, 0, 0, 0);
      a0 = __builtin_amdgcn_mfma_f32_16x16x32_bf16(afr[0][1], b1, a0, 0, 0, 0);
      a1 = __builtin_amdgcn_mfma_f32_16x16x32_bf16(afr[1][0], b0, a1, 0, 0, 0);
      a1 = __builtin_amdgcn_mfma_f32_16x16x32_bf16(afr[1][1], b1, a1, 0, 0, 0);
#pragma unroll
      for (int r = 0; r < 4; ++r) {
        a0[r] = fmaxf(a0[r], 0.f);
        a1[r] = fmaxf(a1[r], 0.f);
        ao[((c0 + kg * 4 + r) << 7) + dt * 16 + col] = a0[r];
        ao[((c0 + 16 + kg * 4 + r) << 7) + dt * 16 + col] = a1[r];
      }
      pa0[dt] = a0;
      pa1[dt] = a1;
    }
  }
  __syncthreads();                                           // B10 (q_t/k_t dead)
  // ---- P10: dw v-h0 -> v_t cols 0..63 (RB); waves 0,1 write a_t half0 (RC)
  {
    float vo[2][8];
    dw_half<false>(halo, wdw + 2 * CC * 9, g0, ch_l, pr, 0, vo, nullptr);
#pragma unroll
    for (int it = 0; it < 2; ++it) {
      int chf = (g0 + 2 * it) * 16 + ch_l;   // 0..63
#pragma unroll
      for (int pc = 0; pc < 8; ++pc)
        *(unsigned short*)(RB + swz256(pr * 8 + pc, chf * 2)) = f2bf(vo[it][pc]);
    }
  }
  if (wv < 2) {
#pragma unroll
    for (int dt = 0; dt < 8; ++dt)
#pragma unroll
      for (int r = 0; r < 4; ++r) {
        int d = dt * 16 + col;
        *(unsigned short*)(RC + swz128(d, (c0 + kg * 4 + r) * 2)) = f2bf(pa0[dt][r]);
        *(unsigned short*)(RC + swz128(d, (c0 + 16 + kg * 4 + r) * 2)) = f2bf(pa1[dt][r]);
      }
  }
  __syncthreads();                                           // B11
  // ---- P11: store v-h1; PV part1 (ks 0,1)
#pragma unroll
  for (int it = 0; it < 8; ++it) hstore(halo, it * 256 + t, pre[it]);
  f32x4 pacc[8];
#pragma unroll
  for (int dt = 0; dt < 8; ++dt) pacc[dt] = {0.f, 0.f, 0.f, 0.f};
#pragma unroll
  for (int ks = 0; ks < 2; ++ks) {
    bf16x8 va = *(const bf16x8*)(RB + swz256(wv * 16 + col, ks * 64 + kg * 16));
#pragma unroll
    for (int dt = 0; dt < 8; ++dt) {
      bf16x8 bf = *(const bf16x8*)(RC + swz128(dt * 16 + col, (ks & 1) * 64 + kg * 16));
      pacc[dt] = __builtin_amdgcn_mfma_f32_16x16x32_bf16(va, bf, pacc[dt], 0, 0, 0);
    }
  }
  __syncthreads();                                           // B12
  // ---- P12: dw v-h1 -> v_t cols 64..127; waves 2,3 write a_t half1
  {
    float vo[2][8];
    dw_half<false>(halo, wdw + 2 * CC * 9, g0, ch_l, pr, 1, vo, nullptr);
#pragma unroll
    for (int it = 0; it < 2; ++it) {
      int chf = 64 + (g0 + 2 * it) * 16 + ch_l;   // 64..127
#pragma unroll
      for (int pc = 0; pc < 8; ++pc)
        *(unsigned short*)(RB + swz256(pr * 8 + pc, chf * 2)) = f2bf(vo[it][pc]);
    }
  }
  if (wv >= 2) {
    int cl0 = c0 - 64;   // 0 or 32
#pragma unroll
    for (int dt = 0; dt < 8; ++dt)
#pragma unroll
      for (int r = 0; r < 4; ++r) {
        int d = dt * 16 + col;
        *(unsigned short*)(RC + swz128(d, (cl0 + kg * 4 + r) * 2)) = f2bf(pa0[dt][r]);
        *(unsigned short*)(RC + swz128(d, (cl0 + 16 + kg * 4 + r) * 2)) = f2bf(pa1[dt][r]);
      }
  }
  __syncthreads();                                           // B13
  // ---- P13: PV part2 (ks 2,3)
#pragma unroll
  for (int ks = 2; ks < 4; ++ks) {
    bf16x8 va = *(const bf16x8*)(RB + swz256(wv * 16 + col, ks * 64 + kg * 16));
#pragma unroll
    for (int dt = 0; dt < 8; ++dt) {
      bf16x8 bf = *(const bf16x8*)(RC + swz128(dt * 16 + col, (ks & 1) * 64 + kg * 16));
      pacc[dt] = __builtin_amdgcn_mfma_f32_16x16x32_bf16(va, bf, pacc[dt], 0, 0, 0);
    }
  }
  __syncthreads();                                           // B14 (v_t dead)
  // ---- P14: po_t[p][d] bf16 (RB, swz256)
#pragma unroll
  for (int dt = 0; dt < 8; ++dt)
#pragma unroll
    for (int r = 0; r < 4; ++r)
      *(unsigned short*)(RB + swz256(wv * 16 + kg * 4 + r, (dt * 16 + col) * 2)) =
          f2bf(pacc[dt][r]);
  __syncthreads();                                           // B15
  // ---- P15: proj (Wp A-frags from global) + fused unwindow/roll y store
  {
    int p = wv * 16 + col;
    bf16x8 bfr[4];
#pragma unroll
    for (int ks = 0; ks < 4; ++ks)
      bfr[ks] = *(const bf16x8*)(RB + swz256(p, ks * 64 + kg * 16));
    int i_f = (((n >> 5) << 3) + (p >> 3) + 4) & 255;
    int j_f = (((n & 31) << 3) + (p & 7) + 4) & 255;
    float* yp = y + (((size_t)b * CC) << 16) + (i_f << 8) + j_f;
#pragma unroll
    for (int mt = 0; mt < 8; ++mt) {
      bf16x8 afr[4];
      const float* wr = wp + (mt * 16 + col) * CC + kg * 8;
#pragma unroll
      for (int ks = 0; ks < 4; ++ks) {
        float wa[4], wb[4];
        *(float4*)wa = *(const float4*)(wr + ks * 32);
        *(float4*)wb = *(const float4*)(wr + ks * 32 + 4);
        bf16x8 f;
#pragma unroll
        for (int e = 0; e < 4; ++e) {
          f[e] = (short)f2bf(wa[e]);
          f[e + 4] = (short)f2bf(wb[e]);
        }
        afr[ks] = f;
      }
      f32x4 acc = {0.f, 0.f, 0.f, 0.f};
#pragma unroll
      for (int ks = 0; ks < 4; ++ks)
        acc = __builtin_amdgcn_mfma_f32_16x16x32_bf16(afr[ks], bfr[ks], acc, 0, 0, 0);
#pragma unroll
      for (int r = 0; r < 4; ++r) {
        int och = mt * 16 + kg * 4 + r;
        yp[(size_t)och << 16] = acc[r];
      }
    }
  }
}

extern "C" void kernel_launch(void* const* d_in, const int* in_sizes, int n_in,
                              void* d_out, int out_size, void* d_ws, size_t ws_size,
                              hipStream_t stream) {
  const float* x = (const float*)d_in[0];
  const float* w_qkv = (const float*)d_in[1];
  const float* w_dw = (const float*)d_in[2];
  const float* w_proj = (const float*)d_in[3];
  const float* temp = (const float*)d_in[4];
  float* y = (float*)d_out;
  float* attn = (float*)d_out + (size_t)NB * CC * HW;   // y first, then attn

  // d_ws (bf16): qkv [3][b][c][hw] = 201 MB.
  __hip_bfloat16* qkv = (__hip_bfloat16*)d_ws;

  k_qkv_mfma<<<2048, 256, 0, stream>>>(x, w_qkv, qkv);
  k_fused<<<4096, 256, 0, stream>>>(qkv, w_dw, temp, w_proj, attn, y);
}

// Round 12
// 696.459 us; speedup vs baseline: 1.3866x; 1.1428x over previous
//
#include <hip/hip_runtime.h>
#include <hip/hip_bf16.h>

// Problem constants
constexpr int NB = 4;        // batch
constexpr int CC = 128;      // channels
constexpr int HW = 65536;    // 256*256 pixels per (b, channel) plane
// windows: 32x32 = 1024 per batch, 8x8 = 64 px per window

using bf16x8 = __attribute__((ext_vector_type(8))) short;   // MFMA A/B frag (4 VGPR)
using f32x4  = __attribute__((ext_vector_type(4))) float;   // MFMA C/D frag

__device__ __forceinline__ unsigned short f2bf(float f) {
  unsigned u = __builtin_bit_cast(unsigned, f);
  u += 0x7FFFu + ((u >> 16) & 1u);
  return (unsigned short)(u >> 16);
}
__device__ __forceinline__ float bf2f(unsigned short s) {
  return __builtin_bit_cast(float, (unsigned)s << 16);
}

// Full 128-ch halo: halo[ch*168 + r*16 + slot], r=0..9 (image row ih0-1+r).
// slot 0..7 window px, 8 = right halo, 9 = left halo. 43008 B.
// 3840 load tasks (128 ch x 10 r x 3 chunks).
__device__ __forceinline__ uint4 hload(const __hip_bfloat16* __restrict__ base,
                                       int ih0, int iw0, int idx) {
  int ch = idx / 30;
  int rem = idx - ch * 30;
  int r = rem / 3, c = rem - r * 3;
  int ii = ih0 - 1 + r, j0 = iw0 - 8 + c * 8;
  uint4 v = {0u, 0u, 0u, 0u};
  if (idx < 3840 && (unsigned)ii < 256u && (unsigned)j0 <= 248u)
    v = *(const uint4*)(base + (((size_t)ch) << 16) + (ii << 8) + j0);
  return v;
}
__device__ __forceinline__ void hstore(unsigned short* __restrict__ halo, int idx, uint4 v) {
  if (idx >= 3840) return;
  int ch = idx / 30;
  int rem = idx - ch * 30;
  int r = rem / 3, c = rem - r * 3;
  unsigned short* hrow = halo + ch * 168 + r * 16;
  if (c == 1) *(uint4*)hrow = v;
  else if (c == 0) hrow[9] = (unsigned short)(v.w >> 16);
  else hrow[8] = (unsigned short)(v.x & 0xFFFFu);
}

// dw 3x3 for one (ch, pr) output row of 8 px.
__device__ __forceinline__ void dw_row(const unsigned short* __restrict__ halo,
                                       const float* __restrict__ wd,
                                       int ch, int pr, float* __restrict__ outv) {
#pragma unroll
  for (int pc = 0; pc < 8; ++pc) outv[pc] = 0.f;
#pragma unroll
  for (int kr = 0; kr < 3; ++kr) {
    const unsigned short* hrow = halo + ch * 168 + (pr + kr) * 16;
    uint4 rw = *(const uint4*)hrow;
    float rv[10];
    rv[0] = bf2f((unsigned short)(rw.x & 0xFFFFu));
    rv[1] = bf2f((unsigned short)(rw.x >> 16));
    rv[2] = bf2f((unsigned short)(rw.y & 0xFFFFu));
    rv[3] = bf2f((unsigned short)(rw.y >> 16));
    rv[4] = bf2f((unsigned short)(rw.z & 0xFFFFu));
    rv[5] = bf2f((unsigned short)(rw.z >> 16));
    rv[6] = bf2f((unsigned short)(rw.w & 0xFFFFu));
    rv[7] = bf2f((unsigned short)(rw.w >> 16));
    rv[8] = bf2f(hrow[8]);
    rv[9] = bf2f(hrow[9]);
#pragma unroll
    for (int s = 0; s < 3; ++s) {
      float wv = wd[kr * 3 + s];
#pragma unroll
      for (int pc = 0; pc < 8; ++pc) {
        int m = pc + s - 1;
        float xv = (m < 0) ? rv[9] : rv[m];
        outv[pc] = fmaf(wv, xv, outv[pc]);
      }
    }
  }
}

// =======================================================================
// Kernel 1: rolled 1x1 conv as bf16 MFMA GEMM (round-9 proven, unchanged).
// =======================================================================
__global__ __launch_bounds__(256) void k_qkv_mfma(const float* __restrict__ x,
                                                  const float* __restrict__ wq,
                                                  __hip_bfloat16* __restrict__ qkv) {
  __shared__ unsigned short x_s[128 * 136];   // [px][c]

  int blk = blockIdx.x;                 // 4 b x 256 i x 2 j-half
  int b = blk >> 9, i = (blk >> 1) & 255, jh = blk & 1;
  int j0 = jh << 7;
  int si = (i + 4) & 255;               // roll(-4): source row
  int t = threadIdx.x;

  {
    int c0 = (t & 63) << 1;
    int jb = (t >> 6) << 5;
    const float* xr0 = x + (((size_t)(b * CC + c0)) << 16) + (si << 8);
    const float* xr1 = xr0 + HW;
#pragma unroll
    for (int u = 0; u < 8; ++u) {
      int jj = jb + (u << 2);
      int sj = j0 + jj + 4;
      float v0[4], v1[4];
      if (sj + 3 <= 255) {
        *(float4*)v0 = *(const float4*)(xr0 + sj);
        *(float4*)v1 = *(const float4*)(xr1 + sj);
      } else {
#pragma unroll
        for (int e = 0; e < 4; ++e) {
          int s = (sj + e) & 255;
          v0[e] = xr0[s];
          v1[e] = xr1[s];
        }
      }
#pragma unroll
      for (int e = 0; e < 4; ++e) {
        unsigned pk = (unsigned)f2bf(v0[e]) | ((unsigned)f2bf(v1[e]) << 16);
        *(unsigned*)&x_s[(jj + e) * 136 + c0] = pk;
      }
    }
  }
  __syncthreads();

  int w = t >> 6;
  int lane = t & 63;
  int col = lane & 15;
  int kg = lane >> 4;

#pragma unroll 1
  for (int oi = 0; oi < 3; ++oi) {
    int m0 = oi * 128 + w * 32;
    bf16x8 afr[2][4];
#pragma unroll
    for (int mt = 0; mt < 2; ++mt) {
      const float* wr = wq + (m0 + mt * 16 + col) * CC + kg * 8;
#pragma unroll
      for (int ks = 0; ks < 4; ++ks) {
        float wa[4], wb[4];
        *(float4*)wa = *(const float4*)(wr + ks * 32);
        *(float4*)wb = *(const float4*)(wr + ks * 32 + 4);
        bf16x8 f;
#pragma unroll
        for (int e = 0; e < 4; ++e) {
          f[e] = (short)f2bf(wa[e]);
          f[e + 4] = (short)f2bf(wb[e]);
        }
        afr[mt][ks] = f;
      }
    }
#pragma unroll 1
    for (int n = 0; n < 8; ++n) {
      int px = n * 16 + col;
      f32x4 acc0 = {0.f, 0.f, 0.f, 0.f};
      f32x4 acc1 = {0.f, 0.f, 0.f, 0.f};
#pragma unroll
      for (int ks = 0; ks < 4; ++ks) {
        bf16x8 bfr = *(const bf16x8*)&x_s[px * 136 + ks * 32 + kg * 8];
        acc0 = __builtin_amdgcn_mfma_f32_16x16x32_bf16(afr[0][ks], bfr, acc0, 0, 0, 0);
        acc1 = __builtin_amdgcn_mfma_f32_16x16x32_bf16(afr[1][ks], bfr, acc1, 0, 0, 0);
      }
      int j = j0 + n * 16 + col;
#pragma unroll
      for (int r = 0; r < 4; ++r) {
        int och0 = m0 + kg * 4 + r;
        int och1 = m0 + 16 + kg * 4 + r;
        int g0 = och0 >> 7, c0 = och0 & 127;
        int g1 = och1 >> 7, c1 = och1 & 127;
        qkv[(((size_t)((g0 * NB + b) * CC + c0)) << 16) + (i << 8) + j] =
            __float2bfloat16(acc0[r]);
        qkv[(((size_t)((g1 * NB + b) * CC + c1)) << 16) + (i << 8) + j] =
            __float2bfloat16(acc1[r]);
      }
    }
  }
}

// =======================================================================
// Kernel 2 (FUSED, 512 threads = 8 waves): round-9 phase structure and LDS
// lifetimes exactly; work remapped to 8 waves (2x issue parallelism/phase),
// halved per-thread register state. 80896 B LDS -> 2 blocks/CU = 16 waves/CU
// (vs round 9's 8). Plain launch_bounds (round-10: a min-occupancy hint
// over-capped VGPR to 84 and spilled 368 MB).
// LDS aliasing: halo(43008): q->k->v halo -> a_t[128][136] -> po_t[64][136]
//               q_t[128][72](18432) -> v_t[64][136](17408); k_t[128][72].
// =======================================================================
__global__ __launch_bounds__(512) void k_fused(const __hip_bfloat16* __restrict__ qkv,
                                               const float* __restrict__ wdw,
                                               const float* __restrict__ temp_p,
                                               const float* __restrict__ wp,
                                               float* __restrict__ attn_out,
                                               float* __restrict__ y) {
  __shared__ unsigned short halo_s[128 * 168];   // 43008 B
  __shared__ unsigned short q_t[128][72];        // 18432 B
  __shared__ unsigned short k_t[128][72];        // 18432 B
  __shared__ float sumsq_s[4][64];               // 1024 B

  int bid = blockIdx.x;
  int blk = ((bid & 7) << 9) + (bid >> 3);   // XCD swizzle (4096 % 8 == 0)
  int b = blk >> 10, n = blk & 1023;
  int ih0 = (n >> 5) << 3, iw0 = (n & 31) << 3;
  int t = threadIdx.x;                        // 0..511
  int ch_l = t & 15, grp = t >> 4;            // grp 0..31
  int pr = grp & 7, contrib = grp >> 3;       // contrib 0..3
  int wv = t >> 6, lane = t & 63;             // wv 0..7
  int col = lane & 15, kg = lane >> 4;
  float tau = temp_p[0];
  const __hip_bfloat16* qb = qkv + (((size_t)(b * CC)) << 16);
  const __hip_bfloat16* kb = qb + (((size_t)(NB * CC)) << 16);
  const __hip_bfloat16* vb = qb + (((size_t)(2 * NB * CC)) << 16);

  uint4 pre[8];
  float outv[2][8];    // 2 dw tasks/thread, persists to the scale phase
  float ssq[8];

  // ---- P0: stage q halo
#pragma unroll
  for (int it = 0; it < 8; ++it) {
    int idx = it * 512 + t;
    hstore(halo_s, idx, hload(qb, ih0, iw0, idx));
  }
  __syncthreads();                               // B1

  // ---- P1: T14 prefetch k halo; dw q (2 tasks) + register sumsq
#pragma unroll
  for (int it = 0; it < 8; ++it) pre[it] = hload(kb, ih0, iw0, it * 512 + t);
#pragma unroll
  for (int pc = 0; pc < 8; ++pc) ssq[pc] = 0.f;
#pragma unroll
  for (int it = 0; it < 2; ++it) {
    int ch = ((contrib + 4 * it) << 4) + ch_l;
    float wd[9];
#pragma unroll
    for (int kk = 0; kk < 9; ++kk) wd[kk] = wdw[ch * 9 + kk];
    dw_row(halo_s, wd, ch, pr, outv[it]);
#pragma unroll
    for (int pc = 0; pc < 8; ++pc) ssq[pc] = fmaf(outv[it][pc], outv[it][pc], ssq[pc]);
  }
#pragma unroll
  for (int pc = 0; pc < 8; ++pc) {
    float s = ssq[pc];
    s += __shfl_xor(s, 1); s += __shfl_xor(s, 2);
    s += __shfl_xor(s, 4); s += __shfl_xor(s, 8);
    ssq[pc] = s;                       // sum over this thread's 32 channels
  }
  if (ch_l == 0) {
#pragma unroll
    for (int pc = 0; pc < 8; ++pc) sumsq_s[contrib][pr * 8 + pc] = ssq[pc];
  }
  __syncthreads();                               // B2

  // ---- P2: write k halo; q scale + q_t write ([c][p])
#pragma unroll
  for (int it = 0; it < 8; ++it) hstore(halo_s, it * 512 + t, pre[it]);
  {
    float psv[8];
#pragma unroll
    for (int pc = 0; pc < 8; ++pc) {
      float s = sumsq_s[0][pr * 8 + pc] + sumsq_s[1][pr * 8 + pc] +
                sumsq_s[2][pr * 8 + pc] + sumsq_s[3][pr * 8 + pc];
      psv[pc] = 1.f / fmaxf(sqrtf(s), 1e-12f);
    }
#pragma unroll
    for (int it = 0; it < 2; ++it) {
      int ch = ((contrib + 4 * it) << 4) + ch_l;
      unsigned short o8[8];
#pragma unroll
      for (int pc = 0; pc < 8; ++pc) o8[pc] = f2bf(outv[it][pc] * psv[pc]);
      *(uint4*)&q_t[ch][pr * 8] = *(const uint4*)o8;
    }
  }
  __syncthreads();                               // B3 (k halo + q_t ready)

  // ---- P3: dw k + register sumsq
#pragma unroll
  for (int pc = 0; pc < 8; ++pc) ssq[pc] = 0.f;
#pragma unroll
  for (int it = 0; it < 2; ++it) {
    int ch = ((contrib + 4 * it) << 4) + ch_l;
    float wd[9];
#pragma unroll
    for (int kk = 0; kk < 9; ++kk) wd[kk] = wdw[(CC + ch) * 9 + kk];
    dw_row(halo_s, wd, ch, pr, outv[it]);
#pragma unroll
    for (int pc = 0; pc < 8; ++pc) ssq[pc] = fmaf(outv[it][pc], outv[it][pc], ssq[pc]);
  }
#pragma unroll
  for (int pc = 0; pc < 8; ++pc) {
    float s = ssq[pc];
    s += __shfl_xor(s, 1); s += __shfl_xor(s, 2);
    s += __shfl_xor(s, 4); s += __shfl_xor(s, 8);
    ssq[pc] = s;
  }
  if (ch_l == 0) {
#pragma unroll
    for (int pc = 0; pc < 8; ++pc) sumsq_s[contrib][pr * 8 + pc] = ssq[pc];
  }
  __syncthreads();                               // B4

  // ---- P4: k scale (tau folded) + k_t write
  {
    float psv[8];
#pragma unroll
    for (int pc = 0; pc < 8; ++pc) {
      float s = sumsq_s[0][pr * 8 + pc] + sumsq_s[1][pr * 8 + pc] +
                sumsq_s[2][pr * 8 + pc] + sumsq_s[3][pr * 8 + pc];
      psv[pc] = tau / fmaxf(sqrtf(s), 1e-12f);
    }
#pragma unroll
    for (int it = 0; it < 2; ++it) {
      int ch = ((contrib + 4 * it) << 4) + ch_l;
      unsigned short o8[8];
#pragma unroll
      for (int pc = 0; pc < 8; ++pc) o8[pc] = f2bf(outv[it][pc] * psv[pc]);
      *(uint4*)&k_t[ch][pr * 8] = *(const uint4*)o8;
    }
  }
  __syncthreads();                               // B5 (k_t ready)

  // ---- P5: T14 prefetch v halo; QK^T (wave = 16-c band); relu; attn write
#pragma unroll
  for (int it = 0; it < 8; ++it) pre[it] = hload(vb, ih0, iw0, it * 512 + t);
  int c0 = wv * 16;
  f32x4 pa[8];
  {
    bf16x8 afr[2];
#pragma unroll
    for (int ks = 0; ks < 2; ++ks)
      afr[ks] = *(const bf16x8*)&q_t[c0 + col][ks * 32 + kg * 8];
    float* ao = attn_out + ((size_t)blk << 14);   // 128*128 per window
#pragma unroll
    for (int dt = 0; dt < 8; ++dt) {
      bf16x8 b0 = *(const bf16x8*)&k_t[dt * 16 + col][kg * 8];
      bf16x8 b1 = *(const bf16x8*)&k_t[dt * 16 + col][32 + kg * 8];
      f32x4 a0 = {0.f, 0.f, 0.f, 0.f};
      a0 = __builtin_amdgcn_mfma_f32_16x16x32_bf16(afr[0], b0, a0, 0, 0, 0);
      a0 = __builtin_amdgcn_mfma_f32_16x16x32_bf16(afr[1], b1, a0, 0, 0, 0);
#pragma unroll
      for (int r = 0; r < 4; ++r) {
        a0[r] = fmaxf(a0[r], 0.f);
        ao[((c0 + kg * 4 + r) << 7) + dt * 16 + col] = a0[r];
      }
      pa[dt] = a0;
    }
  }
  __syncthreads();                               // B6 (q_t/k_t reads done)

  // ---- P6: write v halo
#pragma unroll
  for (int it = 0; it < 8; ++it) hstore(halo_s, it * 512 + t, pre[it]);
  __syncthreads();                               // B7 (v halo ready)

  // ---- dw v -> v_t [p][c] (over dead q_t)
  unsigned short (*v_t)[136] = (unsigned short (*)[136])&q_t[0][0];
#pragma unroll
  for (int it = 0; it < 2; ++it) {
    int ch = ((contrib + 4 * it) << 4) + ch_l;
    float wd[9];
#pragma unroll
    for (int kk = 0; kk < 9; ++kk) wd[kk] = wdw[(2 * CC + ch) * 9 + kk];
    float vo[8];
    dw_row(halo_s, wd, ch, pr, vo);
#pragma unroll
    for (int pc = 0; pc < 8; ++pc) v_t[pr * 8 + pc][ch] = f2bf(vo[pc]);
  }
  __syncthreads();                               // B8 (dw-v halo reads done)

  // ---- P7: a_t[d][c] bf16 from attn regs (over dead halo_s)
  unsigned short (*a_t)[136] = (unsigned short (*)[136])halo_s;
#pragma unroll
  for (int dt = 0; dt < 8; ++dt)
#pragma unroll
    for (int r = 0; r < 4; ++r)
      a_t[dt * 16 + col][c0 + kg * 4 + r] = f2bf(pa[dt][r]);
  __syncthreads();                               // B9 (a_t + v_t ready)

  // ---- P8: PV — wave = (p-tile wv&3, d-half wv>>2)
  int pt = wv & 3, dh = wv >> 2;
  f32x4 pacc[4];
#pragma unroll
  for (int dt = 0; dt < 4; ++dt) pacc[dt] = {0.f, 0.f, 0.f, 0.f};
#pragma unroll
  for (int ks = 0; ks < 4; ++ks) {
    bf16x8 va = *(const bf16x8*)&v_t[pt * 16 + col][ks * 32 + kg * 8];
#pragma unroll
    for (int dt = 0; dt < 4; ++dt) {
      bf16x8 bf = *(const bf16x8*)&a_t[dh * 64 + dt * 16 + col][ks * 32 + kg * 8];
      pacc[dt] = __builtin_amdgcn_mfma_f32_16x16x32_bf16(va, bf, pacc[dt], 0, 0, 0);
    }
  }
  __syncthreads();                               // B10 (a_t reads done)

  // ---- P9: po_t[p][d] bf16 (over dead a_t region)
  unsigned short (*po_t)[136] = (unsigned short (*)[136])halo_s;
#pragma unroll
  for (int dt = 0; dt < 4; ++dt)
#pragma unroll
    for (int r = 0; r < 4; ++r)
      po_t[pt * 16 + kg * 4 + r][dh * 64 + dt * 16 + col] = f2bf(pacc[dt][r]);
  __syncthreads();                               // B11 (po_t ready)

  // ---- P10: proj — wave = (px-tile pt, och-half dh); Wp A-frags from global
  {
    int p = pt * 16 + col;
    bf16x8 bfr[4];
#pragma unroll
    for (int ks = 0; ks < 4; ++ks)
      bfr[ks] = *(const bf16x8*)&po_t[p][ks * 32 + kg * 8];
    int i_f = (((n >> 5) << 3) + (p >> 3) + 4) & 255;
    int j_f = (((n & 31) << 3) + (p & 7) + 4) & 255;
    float* yp = y + (((size_t)b * CC) << 16) + (i_f << 8) + j_f;
#pragma unroll
    for (int mt = 0; mt < 4; ++mt) {
      bf16x8 afr[4];
      const float* wr = wp + (dh * 64 + mt * 16 + col) * CC + kg * 8;
#pragma unroll
      for (int ks = 0; ks < 4; ++ks) {
        float wa[4], wb[4];
        *(float4*)wa = *(const float4*)(wr + ks * 32);
        *(float4*)wb = *(const float4*)(wr + ks * 32 + 4);
        bf16x8 f;
#pragma unroll
        for (int e = 0; e < 4; ++e) {
          f[e] = (short)f2bf(wa[e]);
          f[e + 4] = (short)f2bf(wb[e]);
        }
        afr[ks] = f;
      }
      f32x4 acc = {0.f, 0.f, 0.f, 0.f};
#pragma unroll
      for (int ks = 0; ks < 4; ++ks)
        acc = __builtin_amdgcn_mfma_f32_16x16x32_bf16(afr[ks], bfr[ks], acc, 0, 0, 0);
#pragma unroll
      for (int r = 0; r < 4; ++r) {
        int och = dh * 64 + mt * 16 + kg * 4 + r;
        yp[(size_t)och << 16] = acc[r];
      }
    }
  }
}

extern "C" void kernel_launch(void* const* d_in, const int* in_sizes, int n_in,
                              void* d_out, int out_size, void* d_ws, size_t ws_size,
                              hipStream_t stream) {
  const float* x = (const float*)d_in[0];
  const float* w_qkv = (const float*)d_in[1];
  const float* w_dw = (const float*)d_in[2];
  const float* w_proj = (const float*)d_in[3];
  const float* temp = (const float*)d_in[4];
  float* y = (float*)d_out;
  float* attn = (float*)d_out + (size_t)NB * CC * HW;   // y first, then attn

  // d_ws (bf16): qkv [3][b][c][hw] = 201 MB.
  __hip_bfloat16* qkv = (__hip_bfloat16*)d_ws;

  k_qkv_mfma<<<2048, 256, 0, stream>>>(x, w_qkv, qkv);
  k_fused<<<4096, 512, 0, stream>>>(qkv, w_dw, temp, w_proj, attn, y);
}

// Round 14
// 665.977 us; speedup vs baseline: 1.4501x; 1.0458x over previous
//
#include <hip/hip_runtime.h>
#include <hip/hip_bf16.h>

// Problem constants
constexpr int NB = 4;        // batch
constexpr int CC = 128;      // channels
constexpr int HW = 65536;    // 256*256 pixels per (b, channel) plane
// windows: 32x32 = 1024 per batch, 8x8 = 64 px per window

using bf16x8 = __attribute__((ext_vector_type(8))) short;   // MFMA A/B frag (4 VGPR)
using f32x4  = __attribute__((ext_vector_type(4))) float;   // MFMA C/D frag

__device__ __forceinline__ unsigned short f2bf(float f) {
  unsigned u = __builtin_bit_cast(unsigned, f);
  u += 0x7FFFu + ((u >> 16) & 1u);
  return (unsigned short)(u >> 16);
}
__device__ __forceinline__ float bf2f(unsigned short s) {
  return __builtin_bit_cast(float, (unsigned)s << 16);
}

// Swizzled byte offsets (T2, r11-proven): rows of 128 B / 256 B.
__device__ __forceinline__ int swz128(int row, int b) { return row * 128 + (b ^ ((row & 7) << 4)); }
__device__ __forceinline__ int swz256(int row, int b) { return row * 256 + (b ^ ((row & 15) << 4)); }

// Load the 3 input rows (main 8 px + packed left/right halo) for one (ch, pr)
// dw task straight into registers (no LDS round-trip; zero cross-thread reuse).
__device__ __forceinline__ void dw_load3(const __hip_bfloat16* __restrict__ base,
                                         int ch, int ih0, int iw0, int pr,
                                         uint4* __restrict__ m,
                                         unsigned* __restrict__ lr) {
#pragma unroll
  for (int kr = 0; kr < 3; ++kr) {
    int ii = ih0 + pr - 1 + kr;
    uint4 mv = {0u, 0u, 0u, 0u};
    unsigned lo = 0, hi = 0;
    if ((unsigned)ii < 256u) {
      const __hip_bfloat16* row = base + (((size_t)ch) << 16) + (ii << 8);
      mv = *(const uint4*)(row + iw0);                 // iw0 mult of 8 -> 16B aligned
      if (iw0 > 0)   lo = (unsigned)__builtin_bit_cast(unsigned short, row[iw0 - 1]);
      if (iw0 < 248) hi = (unsigned)__builtin_bit_cast(unsigned short, row[iw0 + 8]);
    }
    m[kr] = mv;
    lr[kr] = lo | (hi << 16);   // low = left halo, high = right halo
  }
}

// dw 3x3 for one (ch, pr) output row of 8 px, inputs in registers.
__device__ __forceinline__ void dw_regs(const uint4* __restrict__ m,
                                        const unsigned* __restrict__ lr,
                                        const float* __restrict__ wd,
                                        float* __restrict__ outv) {
#pragma unroll
  for (int pc = 0; pc < 8; ++pc) outv[pc] = 0.f;
#pragma unroll
  for (int kr = 0; kr < 3; ++kr) {
    uint4 rw = m[kr];
    float rv[10];
    rv[0] = bf2f((unsigned short)(rw.x & 0xFFFFu));
    rv[1] = bf2f((unsigned short)(rw.x >> 16));
    rv[2] = bf2f((unsigned short)(rw.y & 0xFFFFu));
    rv[3] = bf2f((unsigned short)(rw.y >> 16));
    rv[4] = bf2f((unsigned short)(rw.z & 0xFFFFu));
    rv[5] = bf2f((unsigned short)(rw.z >> 16));
    rv[6] = bf2f((unsigned short)(rw.w & 0xFFFFu));
    rv[7] = bf2f((unsigned short)(rw.w >> 16));
    rv[8] = bf2f((unsigned short)(lr[kr] >> 16));      // right
    rv[9] = bf2f((unsigned short)(lr[kr] & 0xFFFFu));  // left
#pragma unroll
    for (int s = 0; s < 3; ++s) {
      float wv = wd[kr * 3 + s];
#pragma unroll
      for (int pc = 0; pc < 8; ++pc) {
        int mm = pc + s - 1;
        float xv = (mm < 0) ? rv[9] : rv[mm];
        outv[pc] = fmaf(wv, xv, outv[pc]);
      }
    }
  }
}

// =======================================================================
// Kernel 1: rolled 1x1 conv as bf16 MFMA GEMM (proven, unchanged).
// =======================================================================
__global__ __launch_bounds__(256) void k_qkv_mfma(const float* __restrict__ x,
                                                  const float* __restrict__ wq,
                                                  __hip_bfloat16* __restrict__ qkv) {
  __shared__ unsigned short x_s[128 * 136];   // [px][c]

  int blk = blockIdx.x;                 // 4 b x 256 i x 2 j-half
  int b = blk >> 9, i = (blk >> 1) & 255, jh = blk & 1;
  int j0 = jh << 7;
  int si = (i + 4) & 255;               // roll(-4): source row
  int t = threadIdx.x;

  {
    int c0 = (t & 63) << 1;
    int jb = (t >> 6) << 5;
    const float* xr0 = x + (((size_t)(b * CC + c0)) << 16) + (si << 8);
    const float* xr1 = xr0 + HW;
#pragma unroll
    for (int u = 0; u < 8; ++u) {
      int jj = jb + (u << 2);
      int sj = j0 + jj + 4;
      float v0[4], v1[4];
      if (sj + 3 <= 255) {
        *(float4*)v0 = *(const float4*)(xr0 + sj);
        *(float4*)v1 = *(const float4*)(xr1 + sj);
      } else {
#pragma unroll
        for (int e = 0; e < 4; ++e) {
          int s = (sj + e) & 255;
          v0[e] = xr0[s];
          v1[e] = xr1[s];
        }
      }
#pragma unroll
      for (int e = 0; e < 4; ++e) {
        unsigned pk = (unsigned)f2bf(v0[e]) | ((unsigned)f2bf(v1[e]) << 16);
        *(unsigned*)&x_s[(jj + e) * 136 + c0] = pk;
      }
    }
  }
  __syncthreads();

  int w = t >> 6;
  int lane = t & 63;
  int col = lane & 15;
  int kg = lane >> 4;

#pragma unroll 1
  for (int oi = 0; oi < 3; ++oi) {
    int m0 = oi * 128 + w * 32;
    bf16x8 afr[2][4];
#pragma unroll
    for (int mt = 0; mt < 2; ++mt) {
      const float* wr = wq + (m0 + mt * 16 + col) * CC + kg * 8;
#pragma unroll
      for (int ks = 0; ks < 4; ++ks) {
        float wa[4], wb[4];
        *(float4*)wa = *(const float4*)(wr + ks * 32);
        *(float4*)wb = *(const float4*)(wr + ks * 32 + 4);
        bf16x8 f;
#pragma unroll
        for (int e = 0; e < 4; ++e) {
          f[e] = (short)f2bf(wa[e]);
          f[e + 4] = (short)f2bf(wb[e]);
        }
        afr[mt][ks] = f;
      }
    }
#pragma unroll 1
    for (int n = 0; n < 8; ++n) {
      int px = n * 16 + col;
      f32x4 acc0 = {0.f, 0.f, 0.f, 0.f};
      f32x4 acc1 = {0.f, 0.f, 0.f, 0.f};
#pragma unroll
      for (int ks = 0; ks < 4; ++ks) {
        bf16x8 bfr = *(const bf16x8*)&x_s[px * 136 + ks * 32 + kg * 8];
        acc0 = __builtin_amdgcn_mfma_f32_16x16x32_bf16(afr[0][ks], bfr, acc0, 0, 0, 0);
        acc1 = __builtin_amdgcn_mfma_f32_16x16x32_bf16(afr[1][ks], bfr, acc1, 0, 0, 0);
      }
      int j = j0 + n * 16 + col;
#pragma unroll
      for (int r = 0; r < 4; ++r) {
        int och0 = m0 + kg * 4 + r;
        int och1 = m0 + 16 + kg * 4 + r;
        int g0 = och0 >> 7, c0 = och0 & 127;
        int g1 = och1 >> 7, c1 = och1 & 127;
        qkv[(((size_t)((g0 * NB + b) * CC + c0)) << 16) + (i << 8) + j] =
            __float2bfloat16(acc0[r]);
        qkv[(((size_t)((g1 * NB + b) * CC + c1)) << 16) + (i << 8) + j] =
            __float2bfloat16(acc1[r]);
      }
    }
  }
}

// =======================================================================
// Kernel 2 (FUSED, register-dw + r11-PROVEN a_t scheme): LDS 33792 B:
//   RB [0,16K):    q_t [128c x 128B swz128] -> v_t [64p x 256B swz256] -> po_t
//   RC [16K,32K):  k_t [swz128] -> a_t half [128d x 64c swz128], TWO passes
//   sq [32K,33K):  [2 g][2 contrib][64 px]
// Round-13 single-pass swz256 a_t (failed 0.117) reverted to r11's two-pass
// swz128 scheme; register-dw retained (audited vs halo path).
// =======================================================================
__global__ __launch_bounds__(256) void k_fused(const __hip_bfloat16* __restrict__ qkv,
                                               const float* __restrict__ wdw,
                                               const float* __restrict__ temp_p,
                                               const float* __restrict__ wp,
                                               float* __restrict__ attn_out,
                                               float* __restrict__ y) {
  __shared__ __align__(16) char smem[33792];
  char* RB = smem;
  char* RC = smem + 16384;
  float* sq = (float*)(smem + 32768);   // 256 floats

  int bid = blockIdx.x;
  int blk = ((bid & 7) << 9) + (bid >> 3);   // XCD swizzle (4096 % 8 == 0)
  int b = blk >> 10, n = blk & 1023;
  int ih0 = (n >> 5) << 3, iw0 = (n & 31) << 3;
  int t = threadIdx.x;
  int ch_l = t & 15, grp = t >> 4;
  int pr = grp & 7, contrib = grp >> 3;      // 4 dw tasks share pr
  int wv = t >> 6, lane = t & 63;
  int col = lane & 15, kg = lane >> 4;
  float tau = temp_p[0];
  const __hip_bfloat16* qb = qkv + (((size_t)(b * CC)) << 16);
  const __hip_bfloat16* kb = qb + (((size_t)(NB * CC)) << 16);
  const __hip_bfloat16* vb = qb + (((size_t)(2 * NB * CC)) << 16);

  uint4 m[12];
  unsigned lr[12];
  float outv[4][8];
  float ssq[8];

  // ---- P0: q loads -> regs; dw q; ssq -> LDS
#pragma unroll
  for (int itk = 0; itk < 4; ++itk) {
    int ch = ((contrib + 2 * itk) << 4) + ch_l;
    dw_load3(qb, ch, ih0, iw0, pr, &m[itk * 3], &lr[itk * 3]);
  }
#pragma unroll
  for (int pc = 0; pc < 8; ++pc) ssq[pc] = 0.f;
#pragma unroll
  for (int itk = 0; itk < 4; ++itk) {
    int ch = ((contrib + 2 * itk) << 4) + ch_l;
    float wd[9];
#pragma unroll
    for (int kk = 0; kk < 9; ++kk) wd[kk] = wdw[ch * 9 + kk];
    dw_regs(&m[itk * 3], &lr[itk * 3], wd, outv[itk]);
#pragma unroll
    for (int pc = 0; pc < 8; ++pc) ssq[pc] = fmaf(outv[itk][pc], outv[itk][pc], ssq[pc]);
  }
#pragma unroll
  for (int pc = 0; pc < 8; ++pc) {
    float s = ssq[pc];
    s += __shfl_xor(s, 1); s += __shfl_xor(s, 2);
    s += __shfl_xor(s, 4); s += __shfl_xor(s, 8);
    ssq[pc] = s;
  }
  if (ch_l == 0) {
#pragma unroll
    for (int pc = 0; pc < 8; ++pc) sq[contrib * 64 + pr * 8 + pc] = ssq[pc];
  }
  __syncthreads();                                   // B1 (q ssq ready)

  // ---- P1: issue k loads; q scale + q_t write; dw k; k ssq -> LDS
  {
    uint4 m2[12];
    unsigned lr2[12];
#pragma unroll
    for (int itk = 0; itk < 4; ++itk) {
      int ch = ((contrib + 2 * itk) << 4) + ch_l;
      dw_load3(kb, ch, ih0, iw0, pr, &m2[itk * 3], &lr2[itk * 3]);
    }
    {
      float psv[8];
#pragma unroll
      for (int pc = 0; pc < 8; ++pc) {
        float s = sq[pr * 8 + pc] + sq[64 + pr * 8 + pc];
        psv[pc] = 1.f / fmaxf(sqrtf(s), 1e-12f);
      }
#pragma unroll
      for (int itk = 0; itk < 4; ++itk) {
        int ch = ((contrib + 2 * itk) << 4) + ch_l;
        unsigned short o8[8];
#pragma unroll
        for (int pc = 0; pc < 8; ++pc) o8[pc] = f2bf(outv[itk][pc] * psv[pc]);
        *(uint4*)(RB + swz128(ch, pr * 16)) = *(const uint4*)o8;
      }
    }
#pragma unroll
    for (int pc = 0; pc < 8; ++pc) ssq[pc] = 0.f;
#pragma unroll
    for (int itk = 0; itk < 4; ++itk) {
      int ch = ((contrib + 2 * itk) << 4) + ch_l;
      float wd[9];
#pragma unroll
      for (int kk = 0; kk < 9; ++kk) wd[kk] = wdw[(CC + ch) * 9 + kk];
      dw_regs(&m2[itk * 3], &lr2[itk * 3], wd, outv[itk]);
#pragma unroll
      for (int pc = 0; pc < 8; ++pc) ssq[pc] = fmaf(outv[itk][pc], outv[itk][pc], ssq[pc]);
    }
  }
#pragma unroll
  for (int pc = 0; pc < 8; ++pc) {
    float s = ssq[pc];
    s += __shfl_xor(s, 1); s += __shfl_xor(s, 2);
    s += __shfl_xor(s, 4); s += __shfl_xor(s, 8);
    ssq[pc] = s;
  }
  if (ch_l == 0) {
#pragma unroll
    for (int pc = 0; pc < 8; ++pc) sq[128 + contrib * 64 + pr * 8 + pc] = ssq[pc];
  }
  __syncthreads();                                   // B2 (k ssq ready)

  // ---- P2: k scale (tau folded) + k_t write
  {
    float psv[8];
#pragma unroll
    for (int pc = 0; pc < 8; ++pc) {
      float s = sq[128 + pr * 8 + pc] + sq[192 + pr * 8 + pc];
      psv[pc] = tau / fmaxf(sqrtf(s), 1e-12f);
    }
#pragma unroll
    for (int itk = 0; itk < 4; ++itk) {
      int ch = ((contrib + 2 * itk) << 4) + ch_l;
      unsigned short o8[8];
#pragma unroll
      for (int pc = 0; pc < 8; ++pc) o8[pc] = f2bf(outv[itk][pc] * psv[pc]);
      *(uint4*)(RC + swz128(ch, pr * 16)) = *(const uint4*)o8;
    }
  }
  __syncthreads();                                   // B3 (q_t + k_t ready)

  // ---- P3: QK^T (r11-proven); relu; attn fp32 write; keep pa; issue v loads
  int c0 = wv * 32;
  f32x4 pa0[8], pa1[8];
  {
    bf16x8 afr[2][2];
#pragma unroll
    for (int mt = 0; mt < 2; ++mt)
#pragma unroll
      for (int ks = 0; ks < 2; ++ks)
        afr[mt][ks] = *(const bf16x8*)(RB + swz128(c0 + mt * 16 + col, ks * 64 + kg * 16));
    float* ao = attn_out + ((size_t)blk << 14);   // 128*128 per window
#pragma unroll
    for (int dt = 0; dt < 8; ++dt) {
      bf16x8 b0 = *(const bf16x8*)(RC + swz128(dt * 16 + col, kg * 16));
      bf16x8 b1 = *(const bf16x8*)(RC + swz128(dt * 16 + col, 64 + kg * 16));
      f32x4 a0 = {0.f, 0.f, 0.f, 0.f};
      f32x4 a1 = {0.f, 0.f, 0.f, 0.f};
      a0 = __builtin_amdgcn_mfma_f32_16x16x32_bf16(afr[0][0], b0, a0, 0, 0, 0);
      a0 = __builtin_amdgcn_mfma_f32_16x16x32_bf16(afr[0][1], b1, a0, 0, 0, 0);
      a1 = __builtin_amdgcn_mfma_f32_16x16x32_bf16(afr[1][0], b0, a1, 0, 0, 0);
      a1 = __builtin_amdgcn_mfma_f32_16x16x32_bf16(afr[1][1], b1, a1, 0, 0, 0);
#pragma unroll
      for (int r = 0; r < 4; ++r) {
        a0[r] = fmaxf(a0[r], 0.f);
        a1[r] = fmaxf(a1[r], 0.f);
        ao[((c0 + kg * 4 + r) << 7) + dt * 16 + col] = a0[r];
        ao[((c0 + 16 + kg * 4 + r) << 7) + dt * 16 + col] = a1[r];
      }
      pa0[dt] = a0;
      pa1[dt] = a1;
    }
  }
#pragma unroll
  for (int itk = 0; itk < 4; ++itk) {
    int ch = ((contrib + 2 * itk) << 4) + ch_l;
    dw_load3(vb, ch, ih0, iw0, pr, &m[itk * 3], &lr[itk * 3]);
  }
  __syncthreads();                                   // B4 (q_t/k_t reads done)

  // ---- P4: dw v -> v_t [p][c] swz256 (over dead q_t); waves 0,1 a_t half0
#pragma unroll
  for (int itk = 0; itk < 4; ++itk) {
    int ch = ((contrib + 2 * itk) << 4) + ch_l;
    float wd[9];
#pragma unroll
    for (int kk = 0; kk < 9; ++kk) wd[kk] = wdw[(2 * CC + ch) * 9 + kk];
    float vo[8];
    dw_regs(&m[itk * 3], &lr[itk * 3], wd, vo);
#pragma unroll
    for (int pc = 0; pc < 8; ++pc)
      *(unsigned short*)(RB + swz256(pr * 8 + pc, ch * 2)) = f2bf(vo[pc]);
  }
  if (wv < 2) {
#pragma unroll
    for (int dt = 0; dt < 8; ++dt)
#pragma unroll
      for (int r = 0; r < 4; ++r) {
        int d = dt * 16 + col;
        *(unsigned short*)(RC + swz128(d, (c0 + kg * 4 + r) * 2)) = f2bf(pa0[dt][r]);
        *(unsigned short*)(RC + swz128(d, (c0 + 16 + kg * 4 + r) * 2)) = f2bf(pa1[dt][r]);
      }
  }
  __syncthreads();                                   // B5 (v_t + a_t half0 ready)

  // ---- P5: PV part1 (ks 0,1 -> c 0..63)
  f32x4 pacc[8];
#pragma unroll
  for (int dt = 0; dt < 8; ++dt) pacc[dt] = {0.f, 0.f, 0.f, 0.f};
#pragma unroll
  for (int ks = 0; ks < 2; ++ks) {
    bf16x8 va = *(const bf16x8*)(RB + swz256(wv * 16 + col, ks * 64 + kg * 16));
#pragma unroll
    for (int dt = 0; dt < 8; ++dt) {
      bf16x8 bf = *(const bf16x8*)(RC + swz128(dt * 16 + col, (ks & 1) * 64 + kg * 16));
      pacc[dt] = __builtin_amdgcn_mfma_f32_16x16x32_bf16(va, bf, pacc[dt], 0, 0, 0);
    }
  }
  __syncthreads();                                   // B6 (half0 reads done)

  // ---- P6: waves 2,3 write a_t half1 (c 64..127)
  if (wv >= 2) {
    int cl0 = c0 - 64;   // 0 or 32
#pragma unroll
    for (int dt = 0; dt < 8; ++dt)
#pragma unroll
      for (int r = 0; r < 4; ++r) {
        int d = dt * 16 + col;
        *(unsigned short*)(RC + swz128(d, (cl0 + kg * 4 + r) * 2)) = f2bf(pa0[dt][r]);
        *(unsigned short*)(RC + swz128(d, (cl0 + 16 + kg * 4 + r) * 2)) = f2bf(pa1[dt][r]);
      }
  }
  __syncthreads();                                   // B7 (a_t half1 ready)

  // ---- P7: PV part2 (ks 2,3 -> c 64..127)
#pragma unroll
  for (int ks = 2; ks < 4; ++ks) {
    bf16x8 va = *(const bf16x8*)(RB + swz256(wv * 16 + col, ks * 64 + kg * 16));
#pragma unroll
    for (int dt = 0; dt < 8; ++dt) {
      bf16x8 bf = *(const bf16x8*)(RC + swz128(dt * 16 + col, (ks & 1) * 64 + kg * 16));
      pacc[dt] = __builtin_amdgcn_mfma_f32_16x16x32_bf16(va, bf, pacc[dt], 0, 0, 0);
    }
  }
  __syncthreads();                                   // B8 (v_t reads done)

  // ---- P8: po_t [p][d] swz256 (over dead v_t)
#pragma unroll
  for (int dt = 0; dt < 8; ++dt)
#pragma unroll
    for (int r = 0; r < 4; ++r)
      *(unsigned short*)(RB + swz256(wv * 16 + kg * 4 + r, (dt * 16 + col) * 2)) =
          f2bf(pacc[dt][r]);
  __syncthreads();                                   // B9 (po_t ready)

  // ---- P9: proj (Wp A-frags from global, L2-resident) + fused unwindow/roll
  {
    int p = wv * 16 + col;
    bf16x8 bfr[4];
#pragma unroll
    for (int ks = 0; ks < 4; ++ks)
      bfr[ks] = *(const bf16x8*)(RB + swz256(p, ks * 64 + kg * 16));
    int i_f = (((n >> 5) << 3) + (p >> 3) + 4) & 255;
    int j_f = (((n & 31) << 3) + (p & 7) + 4) & 255;
    float* yp = y + (((size_t)b * CC) << 16) + (i_f << 8) + j_f;
#pragma unroll
    for (int mt = 0; mt < 8; ++mt) {
      bf16x8 afr[4];
      const float* wr = wp + (mt * 16 + col) * CC + kg * 8;
#pragma unroll
      for (int ks = 0; ks < 4; ++ks) {
        float wa[4], wb[4];
        *(float4*)wa = *(const float4*)(wr + ks * 32);
        *(float4*)wb = *(const float4*)(wr + ks * 32 + 4);
        bf16x8 f;
#pragma unroll
        for (int e = 0; e < 4; ++e) {
          f[e] = (short)f2bf(wa[e]);
          f[e + 4] = (short)f2bf(wb[e]);
        }
        afr[ks] = f;
      }
      f32x4 acc = {0.f, 0.f, 0.f, 0.f};
#pragma unroll
      for (int ks = 0; ks < 4; ++ks)
        acc = __builtin_amdgcn_mfma_f32_16x16x32_bf16(afr[ks], bfr[ks], acc, 0, 0, 0);
#pragma unroll
      for (int r = 0; r < 4; ++r) {
        int och = mt * 16 + kg * 4 + r;
        yp[(size_t)och << 16] = acc[r];
      }
    }
  }
}

extern "C" void kernel_launch(void* const* d_in, const int* in_sizes, int n_in,
                              void* d_out, int out_size, void* d_ws, size_t ws_size,
                              hipStream_t stream) {
  const float* x = (const float*)d_in[0];
  const float* w_qkv = (const float*)d_in[1];
  const float* w_dw = (const float*)d_in[2];
  const float* w_proj = (const float*)d_in[3];
  const float* temp = (const float*)d_in[4];
  float* y = (float*)d_out;
  float* attn = (float*)d_out + (size_t)NB * CC * HW;   // y first, then attn

  // d_ws (bf16): qkv [3][b][c][hw] = 201 MB.
  __hip_bfloat16* qkv = (__hip_bfloat16*)d_ws;

  k_qkv_mfma<<<2048, 256, 0, stream>>>(x, w_qkv, qkv);
  k_fused<<<4096, 256, 0, stream>>>(qkv, w_dw, temp, w_proj, attn, y);
}